// Round 4
// baseline (211.201 us; speedup 1.0000x reference)
//
#include <hip/hip_runtime.h>
#include <hip/hip_bf16.h>

#define BB 4
#define NN 200
#define HH 300
#define KS 10    // k-steps of 32 (K padded to 320)
#define GF 20    // g-frags of 16 (G padded to 320, frag 19 is zeros)
#define ALD 328  // A LDS row stride in bf16 (656 B: 16B-aligned, 2-way banks)

typedef __attribute__((ext_vector_type(8))) short short8;
typedef __attribute__((ext_vector_type(4))) short short4v;
typedef __attribute__((ext_vector_type(4))) float float4v;

static __device__ __forceinline__ ushort f2bf(float x) {
    union { float f; uint u; } v; v.f = x;
    uint r = v.u + 0x7FFFu + ((v.u >> 16) & 1u);  // RNE
    return (ushort)(r >> 16);
}

// Pack U_w (g,h) f32 -> bf16 in MFMA B-fragment order:
// Bp[((ks*GF+gf)*64 + lane)*8 + j] = Uw[g=gf*16+(lane&15)][h=ks*32+(lane>>4)*8+j], 0 if OOB
__global__ void pack_u(const float* __restrict__ Uw, ushort* __restrict__ Bp) {
    int idx = blockIdx.x * 256 + threadIdx.x;
    if (idx >= KS * GF * 64) return;
    int lane = idx & 63;
    int kg = idx >> 6;
    int gf = kg % GF, ks = kg / GF;
    int g = gf * 16 + (lane & 15);
    int h0 = ks * 32 + (lane >> 4) * 8;
    ushort v[8];
#pragma unroll
    for (int j = 0; j < 8; ++j) {
        int h = h0 + j;
        v[j] = (g < HH && h < HH) ? f2bf(Uw[g * HH + h]) : (ushort)0;
    }
    *reinterpret_cast<short8*>(Bp + (size_t)idx * 8) = *reinterpret_cast<const short8*>(v);
}

// Vx[b,n,g] = sum_h x[b,n,h]*Vw[g,h] + Vb[g]   (f32, tiny)
__global__ void vx_kernel(const float* __restrict__ x, const float* __restrict__ Vw,
                          const float* __restrict__ Vb, float* __restrict__ Vx) {
    __shared__ float xs[HH];
    int row = blockIdx.x;  // b*N + n
    const float* xr = x + (size_t)row * HH;
    for (int h = threadIdx.x; h < HH; h += 256) xs[h] = xr[h];
    __syncthreads();
    for (int g = threadIdx.x; g < HH; g += 256) {
        const float4* wr = reinterpret_cast<const float4*>(Vw + (size_t)g * HH);
        const float4* xv = reinterpret_cast<const float4*>(xs);
        float s0 = 0.f, s1 = 0.f, s2 = 0.f, s3 = 0.f;
#pragma unroll 5
        for (int k = 0; k < HH / 4; ++k) {
            float4 w = wr[k];
            float4 xx = xv[k];
            s0 += w.x * xx.x; s1 += w.y * xx.y; s2 += w.z * xx.z; s3 += w.w * xx.w;
        }
        Vx[(size_t)row * HH + g] = Vb[g] + s0 + s1 + s2 + s3;
    }
}

// Block = 32 rows x full G(320). 4 waves: (row-half) x (g-half).
// Each wave: 16 rows x 10 g-frags -> acc 40 VGPR. A staged once in LDS (bf16),
// B frag-packed in L2. Target: <=128 regs/wave -> 4 waves/SIMD.
__launch_bounds__(256, 4)
__global__ void gemm_kernel(const float* __restrict__ e, const ushort* __restrict__ Bp,
                            const float* __restrict__ Ub, const float* __restrict__ Vx,
                            float* __restrict__ out) {
    __shared__ ushort Alds[32 * ALD];
    const int tid = threadIdx.x;
    const int lane = tid & 63, wave = tid >> 6;
    const int m0blk = blockIdx.x * 32;

    // Stage A: contiguous flat float4 copy of e[m0blk .. m0blk+32) (32*300 f32),
    // converted to bf16 into LDS [32][ALD].
    const float* eb = e + (size_t)m0blk * HH;
#pragma unroll
    for (int i = 0; i < 10; ++i) {
        int f4 = tid + i * 256;
        if (f4 < (32 * HH) / 4) {
            int f = f4 * 4;
            int row = f / HH;
            int col = f - row * HH;   // multiple of 4
            float4 v = *reinterpret_cast<const float4*>(eb + f);
            short4v w;
            w[0] = (short)f2bf(v.x); w[1] = (short)f2bf(v.y);
            w[2] = (short)f2bf(v.z); w[3] = (short)f2bf(v.w);
            *reinterpret_cast<short4v*>(&Alds[row * ALD + col]) = w;
        }
    }
    // zero-pad cols [300, 328) for all 32 rows (14 u32 per row)
    for (int idx = tid; idx < 32 * 14; idx += 256) {
        int row = idx / 14;
        int c = 300 + (idx % 14) * 2;
        *reinterpret_cast<uint*>(&Alds[row * ALD + c]) = 0u;
    }
    __syncthreads();

    const int rowhalf = wave & 1, ghalf = wave >> 1;
    const int gfbase = ghalf * 10;
    const int r = lane & 15, q = lane >> 4;
    const int arow = rowhalf * 16 + r;

    float4v acc[10];
#pragma unroll
    for (int gf = 0; gf < 10; ++gf) acc[gf] = (float4v){0.f, 0.f, 0.f, 0.f};

    const short8* bp = reinterpret_cast<const short8*>(Bp);

#pragma unroll 1
    for (int ks = 0; ks < KS; ++ks) {
        short8 fa = *reinterpret_cast<const short8*>(&Alds[arow * ALD + ks * 32 + q * 8]);
#pragma unroll
        for (int c = 0; c < 2; ++c) {
            short8 bf[5];
#pragma unroll
            for (int u = 0; u < 5; ++u)
                bf[u] = bp[(size_t)((ks * GF + gfbase + c * 5 + u) * 64 + lane)];
#pragma unroll
            for (int u = 0; u < 5; ++u)
                acc[c * 5 + u] =
                    __builtin_amdgcn_mfma_f32_16x16x32_bf16(fa, bf[u], acc[c * 5 + u], 0, 0, 0);
        }
    }

    // Epilogue: + Ub + Vx[i-row] + Vx[j-row], masked store g<300
    const int mt = m0blk + rowhalf * 16;
    const int rg = q * 4;
#pragma unroll
    for (int r4 = 0; r4 < 4; ++r4) {
        int m = mt + rg + r4;
        int j = m % NN;
        int t = m / NN;       // b*NN + i
        int b = t / NN;
        const float* vi = Vx + (size_t)t * HH;
        const float* vj = Vx + (size_t)(b * NN + j) * HH;
        float* orow = out + (size_t)m * HH;
#pragma unroll
        for (int gf = 0; gf < 10; ++gf) {
            int g = (gfbase + gf) * 16 + r;
            if (g < HH)
                orow[g] = acc[gf][r4] + Ub[g] + vi[g] + vj[g];
        }
    }
}

extern "C" void kernel_launch(void* const* d_in, const int* in_sizes, int n_in,
                              void* d_out, int out_size, void* d_ws, size_t ws_size,
                              hipStream_t stream) {
    const float* x  = (const float*)d_in[0];
    const float* e  = (const float*)d_in[1];
    const float* Uw = (const float*)d_in[2];
    const float* Ub = (const float*)d_in[3];
    const float* Vw = (const float*)d_in[4];
    const float* Vb = (const float*)d_in[5];
    float* out = (float*)d_out;

    ushort* Bp = (ushort*)d_ws;                          // 204,800 B (frag-packed bf16 U_w, GF=20)
    float*  Vx = (float*)((char*)d_ws + 204800);         // 960,000 B

    pack_u<<<50, 256, 0, stream>>>(Uw, Bp);
    vx_kernel<<<BB * NN, 256, 0, stream>>>(x, Vw, Vb, Vx);
    gemm_kernel<<<5000, 256, 0, stream>>>(e, Bp, Ub, Vx, out);
}

// Round 5
// 198.804 us; speedup vs baseline: 1.0624x; 1.0624x over previous
//
#include <hip/hip_runtime.h>
#include <hip/hip_bf16.h>

#define BB 4
#define NN 200
#define HH 300
#define KSN 10    // k-steps of 32 (K padded to 320)
#define GFULL 20  // total g-frags of 16 (G padded to 320; frag 19 zero)
#define GHF 10    // g-frags per g-half block

typedef __attribute__((ext_vector_type(8))) short short8;
typedef __attribute__((ext_vector_type(4))) float float4v;

static __device__ __forceinline__ ushort f2bf(float x) {
    union { float f; uint u; } v; v.f = x;
    uint r = v.u + 0x7FFFu + ((v.u >> 16) & 1u);  // RNE
    return (ushort)(r >> 16);
}

static __device__ __forceinline__ short8 pack8(float4v a, float4v b) {
    short8 r;
    r[0] = (short)f2bf(a[0]); r[1] = (short)f2bf(a[1]);
    r[2] = (short)f2bf(a[2]); r[3] = (short)f2bf(a[3]);
    r[4] = (short)f2bf(b[0]); r[5] = (short)f2bf(b[1]);
    r[6] = (short)f2bf(b[2]); r[7] = (short)f2bf(b[3]);
    return r;
}

static __device__ __forceinline__ void gload_lds16(const void* g, void* l) {
    __builtin_amdgcn_global_load_lds(
        (const __attribute__((address_space(1))) unsigned int*)g,
        (__attribute__((address_space(3))) unsigned int*)l, 16, 0, 0);
}

// Pack U_w (g,h) f32 -> bf16 in MFMA B-fragment order:
// Bp[((ks*GFULL+gf)*64 + lane)*8 + j] = Uw[g=gf*16+(lane&15)][h=ks*32+(lane>>4)*8+j]
__global__ void pack_u(const float* __restrict__ Uw, ushort* __restrict__ Bp) {
    int idx = blockIdx.x * 256 + threadIdx.x;
    if (idx >= KSN * GFULL * 64) return;
    int lane = idx & 63;
    int kg = idx >> 6;
    int gf = kg % GFULL, ks = kg / GFULL;
    int g = gf * 16 + (lane & 15);
    int h0 = ks * 32 + (lane >> 4) * 8;
    ushort v[8];
#pragma unroll
    for (int j = 0; j < 8; ++j) {
        int h = h0 + j;
        v[j] = (g < HH && h < HH) ? f2bf(Uw[g * HH + h]) : (ushort)0;
    }
    *reinterpret_cast<short8*>(Bp + (size_t)idx * 8) = *reinterpret_cast<const short8*>(v);
}

// Vx[b,n,g] = sum_h x[b,n,h]*Vw[g,h] + Vb[g]
__global__ void vx_kernel(const float* __restrict__ x, const float* __restrict__ Vw,
                          const float* __restrict__ Vb, float* __restrict__ Vx) {
    __shared__ float xs[HH];
    int row = blockIdx.x;
    const float* xr = x + (size_t)row * HH;
    for (int h = threadIdx.x; h < HH; h += 256) xs[h] = xr[h];
    __syncthreads();
    for (int g = threadIdx.x; g < HH; g += 256) {
        const float4* wr = reinterpret_cast<const float4*>(Vw + (size_t)g * HH);
        const float4* xv = reinterpret_cast<const float4*>(xs);
        float s0 = 0.f, s1 = 0.f, s2 = 0.f, s3 = 0.f;
#pragma unroll 5
        for (int k = 0; k < HH / 4; ++k) {
            float4 w = wr[k];
            float4 xx = xv[k];
            s0 += w.x * xx.x; s1 += w.y * xx.y; s2 += w.z * xx.z; s3 += w.w * xx.w;
        }
        Vx[(size_t)row * HH + g] = Vb[g] + s0 + s1 + s2 + s3;
    }
}

// Block = 64 rows x half-G (10 frags). 4 waves = 4 row-quads, each 16 rows x 10 frags.
// B staged per-ks into LDS via async global_load_lds (double-buffered, counted vmcnt).
// A per-wave from global (f32 -> bf16 in reg), prefetched one ks ahead.
__launch_bounds__(256, 4)
__global__ void gemm_kernel(const float* __restrict__ e, const ushort* __restrict__ Bp,
                            const float* __restrict__ Ub, const float* __restrict__ Vx,
                            float* __restrict__ out) {
    // per buffer: 10 frags * 1024B = 10240B used + 2048B pad (uniform 3-round staging)
    __shared__ ushort Blds[2][6144];
    const int tid = threadIdx.x;
    const int lane = tid & 63, wave = tid >> 6;
    const int gh = blockIdx.x & 1;
    const int mtile = blockIdx.x >> 1;
    const int m0 = mtile * 64;
    const int r = lane & 15, q = lane >> 4;
    const int arow = m0 + wave * 16 + r;
    const float* rowp = e + (size_t)arow * HH;
    const char* bsrc_base = (const char*)Bp + (size_t)gh * (GHF * 1024);

    float4v acc[GHF];
#pragma unroll
    for (int f = 0; f < GHF; ++f) acc[f] = (float4v){0.f, 0.f, 0.f, 0.f};

    float4v pa0, pb0, pa1, pb1;

    // stage B(ks) -> Blds[P]: 3 uniform gload_lds rounds (waves 2,3 round-3 writes pad)
#define ISSUE_B(KS_, P_) do {                                                   \
        const char* s_ = bsrc_base + (size_t)(KS_) * (GFULL * 1024);            \
        char* l_ = (char*)&Blds[P_][0];                                         \
        gload_lds16(s_ + tid * 16,                l_ + wave * 1024);            \
        gload_lds16(s_ + 4096 + tid * 16,         l_ + 4096 + wave * 1024);     \
        gload_lds16(s_ + 8192 + (tid & 127) * 16, l_ + 8192 + wave * 1024);     \
    } while (0)

    // A(ks): 2 float4 per lane; second clamped to e-base when cols >= 300 (B=0 there)
#define LOAD_A(KS_, PA_, PB_) do {                                              \
        int c0_ = (KS_) * 32 + q * 8;                                           \
        PA_ = *reinterpret_cast<const float4v*>(rowp + c0_);                    \
        const float* p2_ = (c0_ + 8 <= HH) ? (rowp + c0_ + 4) : e;              \
        PB_ = *reinterpret_cast<const float4v*>(p2_);                           \
    } while (0)

#define BODY(KS_, P_, PA_, PB_, ISSUE_, WAITN_) do {                            \
        asm volatile("s_waitcnt vmcnt(" #WAITN_ ")" ::: "memory");              \
        __builtin_amdgcn_sched_barrier(0);                                      \
        __builtin_amdgcn_s_barrier();                                           \
        __builtin_amdgcn_sched_barrier(0);                                      \
        short8 fa_ = pack8(PA_, PB_);                                           \
        const ushort* bb_ = &Blds[P_][0];                                       \
        _Pragma("unroll")                                                       \
        for (int f_ = 0; f_ < GHF; ++f_) {                                      \
            short8 bf_ = *reinterpret_cast<const short8*>(bb_ + f_ * 512 + lane * 8); \
            acc[f_] = __builtin_amdgcn_mfma_f32_16x16x32_bf16(fa_, bf_, acc[f_], 0, 0, 0); \
        }                                                                       \
        __builtin_amdgcn_sched_barrier(0);                                      \
        __builtin_amdgcn_s_barrier();                                           \
        __builtin_amdgcn_sched_barrier(0);                                      \
        if (ISSUE_) { ISSUE_B((KS_) + 2, P_); LOAD_A((KS_) + 2, PA_, PB_); }    \
    } while (0)

    // prologue: two groups of (3 B-gloads + 2 A-loads) = 10 outstanding
    ISSUE_B(0, 0); LOAD_A(0, pa0, pb0);
    asm volatile("" ::: "memory");
    __builtin_amdgcn_sched_barrier(0);
    ISSUE_B(1, 1); LOAD_A(1, pa1, pb1);
    asm volatile("" ::: "memory");
    __builtin_amdgcn_sched_barrier(0);

#pragma unroll 1
    for (int kk = 0; kk < 4; ++kk) {
        const int ks0 = kk * 2;
        BODY(ks0, 0, pa0, pb0, 1, 5);
        BODY(ks0 + 1, 1, pa1, pb1, 1, 5);
    }
    BODY(8, 0, pa0, pb0, 0, 5);
    BODY(9, 1, pa1, pb1, 0, 0);

    // Epilogue: + Ub + Vx[i-row] + Vx[j-row], masked store g<300
    const int gbase = gh * 160;
#pragma unroll
    for (int r4 = 0; r4 < 4; ++r4) {
        int m = m0 + wave * 16 + q * 4 + r4;
        int j = m % NN;
        int t = m / NN;       // b*NN + i
        int b = t / NN;
        const float* vi = Vx + (size_t)t * HH;
        const float* vj = Vx + (size_t)(b * NN + j) * HH;
        float* orow = out + (size_t)m * HH;
#pragma unroll
        for (int f = 0; f < GHF; ++f) {
            int g = gbase + f * 16 + r;
            if (g < HH)
                orow[g] = acc[f][r4] + Ub[g] + vi[g] + vj[g];
        }
    }
}

extern "C" void kernel_launch(void* const* d_in, const int* in_sizes, int n_in,
                              void* d_out, int out_size, void* d_ws, size_t ws_size,
                              hipStream_t stream) {
    const float* x  = (const float*)d_in[0];
    const float* e  = (const float*)d_in[1];
    const float* Uw = (const float*)d_in[2];
    const float* Ub = (const float*)d_in[3];
    const float* Vw = (const float*)d_in[4];
    const float* Vb = (const float*)d_in[5];
    float* out = (float*)d_out;

    ushort* Bp = (ushort*)d_ws;                          // 204,800 B (frag-packed bf16 U_w, GF=20)
    float*  Vx = (float*)((char*)d_ws + 204800);         // 960,000 B

    pack_u<<<50, 256, 0, stream>>>(Uw, Bp);
    vx_kernel<<<BB * NN, 256, 0, stream>>>(x, Vw, Vb, Vx);
    // 2500 m-tiles x 2 g-halves; gh = bit0 so twin blocks (same e rows) are adjacent
    gemm_kernel<<<5000, 256, 0, stream>>>(e, Bp, Ub, Vx, out);
}